// Round 5
// baseline (661.613 us; speedup 1.0000x reference)
//
#include <hip/hip_runtime.h>
#include <hip/hip_bf16.h>

#define NLAYERS 3
#define BB 32
#define LL 336
#define NN 321
#define EE 4
#define DHID 512
#define PP 96
#define STOT (BB*NN*LL)        // 3451392
#define MROWS (BB*NN)          // 10272
#define BPN ((size_t)BB*PP*NN) // 986112

typedef __attribute__((ext_vector_type(8))) short short8;
typedef __attribute__((ext_vector_type(4))) float float4v;

union S8 { short8 v; uint4 u; short s[8]; };
union BF { __hip_bfloat16 h; short s; };

__device__ __forceinline__ short f2b(float f) { BF u; u.h = __float2bfloat16(f); return u.s; }

__device__ __forceinline__ float fast_tanh(float y) {
    float e = __expf(2.0f * y);
    return 1.0f - 2.0f / (e + 1.0f);   // exact limits at +-inf
}
__device__ __forceinline__ float gelu_f(float x) {
    return 0.5f * x * (1.0f + fast_tanh(0.7978845608028654f * (x + 0.044715f * x * x * x)));
}
__device__ __forceinline__ float softplus_f(float x) {
    return fmaxf(x, 0.0f) + log1pf(expf(-fabsf(x)));
}

// ---------------- RevIN stats: mu/inv per (b,n); also zeros loss ----------------
// grid (BB, 6), 256 thr = 64 n x 4 l-chunks of 84
__global__ __launch_bounds__(256) void revin_stats(
    const float* __restrict__ x, float* __restrict__ MU, float* __restrict__ IV,
    float* __restrict__ loss)
{
    int b = blockIdx.x, nt = blockIdx.y;
    int tid = threadIdx.x;
    if (b == 0 && nt == 0 && tid == 0) loss[0] = 0.0f;
    int ni = tid & 63, lc = tid >> 6;
    int n = nt * 64 + ni;
    float s = 0.f, ss = 0.f;
    if (n < NN) {
        const float* xp = x + ((size_t)b * LL + lc * 84) * NN + n;
        for (int l = 0; l < 84; ++l, xp += NN) {
            float v = *xp; s += v; ss = fmaf(v, v, ss);
        }
    }
    __shared__ float Ss[4][64], Sq[4][64];
    Ss[lc][ni] = s; Sq[lc][ni] = ss;
    __syncthreads();
    if (lc == 0 && n < NN) {
        float st = ((Ss[0][ni] + Ss[1][ni]) + Ss[2][ni]) + Ss[3][ni];
        float sq = ((Sq[0][ni] + Sq[1][ni]) + Sq[2][ni]) + Sq[3][ni];
        float mu  = st * (1.0f / LL);
        float var = sq * (1.0f / LL) - mu * mu;   // ddof=0
        float inv = 1.0f / sqrtf(var + 1e-5f);
        MU[b * NN + n] = mu;
        IV[b * NN + n] = inv;
    }
}

// ---------------- RevIN transpose+normalize: T[b*NN+n][l] (fp32+bf16) ----------------
// grid (BB, 6, 7): 64-node x 48-l tiles; coalesced loads and 64B-aligned stores
__global__ __launch_bounds__(256) void revin_tn(
    const float* __restrict__ x, const float* __restrict__ MU, const float* __restrict__ IV,
    float* __restrict__ T, short* __restrict__ Tb16)
{
    int b = blockIdx.x, nt = blockIdx.y, lt = blockIdx.z;
    int n0 = nt * 64, l0 = lt * 48;
    __shared__ float Ls[48][65];
    int tid = threadIdx.x;
    #pragma unroll
    for (int i = 0; i < 12; ++i) {
        int lin = tid + i * 256;
        int li = lin >> 6, ni = lin & 63;
        int n = n0 + ni;
        Ls[li][ni] = (n < NN) ? x[((size_t)b * LL + l0 + li) * NN + n] : 0.f;
    }
    __syncthreads();
    int r = tid >> 2, q = tid & 3;
    int n = n0 + r;
    if (n >= NN) return;
    float mu = MU[b * NN + n], iv = IV[b * NN + n];
    size_t row = (size_t)(b * NN + n) * LL + l0;
    #pragma unroll
    for (int k = 0; k < 3; ++k) {
        int c = (q + 4 * k) * 4;
        float4 v;
        v.x = (Ls[c    ][r] - mu) * iv;
        v.y = (Ls[c + 1][r] - mu) * iv;
        v.z = (Ls[c + 2][r] - mu) * iv;
        v.w = (Ls[c + 3][r] - mu) * iv;
        *(float4*)&T[row + c] = v;
        union { short s[4]; uint2 u; } pk;
        pk.s[0] = f2b(v.x); pk.s[1] = f2b(v.y); pk.s[2] = f2b(v.z); pk.s[3] = f2b(v.w);
        *(uint2*)&Tb16[row + c] = pk.u;
    }
}

// ---------------- tiled transpose+convert: dst[d][k] <- bf16(src[k][d]) ----------------
// grid (ceil(D/64), ceil(K/64), n_slices)
__global__ __launch_bounds__(256) void wtrans_kernel(
    const float* __restrict__ src0, short* __restrict__ dst0, int K, int D)
{
    int le = blockIdx.z;
    const float* src = src0 + (size_t)le * K * D;
    short* dst = dst0 + (size_t)le * K * D;
    int d0 = blockIdx.x * 64, k0 = blockIdx.y * 64;
    __shared__ short Ws[64][72];
    int tid = threadIdx.x;
    #pragma unroll
    for (int i = 0; i < 16; ++i) {
        int lin = tid + i * 256;
        int ki = lin >> 6, dj = lin & 63;
        int k = k0 + ki, d = d0 + dj;
        Ws[ki][dj] = (k < K && d < D) ? f2b(src[(size_t)k * D + d]) : (short)0;
    }
    __syncthreads();
    int di = tid >> 2, d = d0 + di;
    if (d >= D) return;
    #pragma unroll
    for (int kp = 0; kp < 2; ++kp) {
        int kj = ((tid & 3) + 4 * kp) * 8;
        if (k0 + kj >= K) continue;
        union { short s[8]; uint4 u; } pk;
        #pragma unroll
        for (int j = 0; j < 8; ++j) pk.s[j] = Ws[kj + j][di];
        *(uint4*)(dst + (size_t)d * K + k0 + kj) = pk.u;
    }
}

// ---------------- small convert for p1w/p2w (already [n][k]) ----------------
__global__ __launch_bounds__(256) void pcvt_kernel(
    const float* __restrict__ p1w, const float* __restrict__ p2w,
    short* __restrict__ p1wb, short* __restrict__ p2wb)
{
    int i = blockIdx.x * 256 + threadIdx.x;
    if (i < PP * LL) p1wb[i] = f2b(p1w[i]);
    else if (i < PP * LL + 2 * PP * PP) { int j = i - PP * LL; p2wb[j] = f2b(p2w[j]); }
}

// ---------------- gate features: 8-way partial sums over n ----------------
__global__ __launch_bounds__(384) void gmean_part(
    const float* __restrict__ T, float* __restrict__ G8)
{
    int b = blockIdx.x, c = blockIdx.y;
    int l = threadIdx.x;
    if (l >= LL) return;
    int n_lo = c * 41, n_hi = (NN < n_lo + 41) ? NN : (n_lo + 41);
    const float* tp = T + ((size_t)b * NN + n_lo) * LL + l;
    float s = 0.f;
    for (int n = n_lo; n < n_hi; ++n, tp += LL) s += *tp;
    G8[((size_t)c * BB + b) * LL + l] = s;
}

// ---------------- fused gmean-reduce + noisy top-k gating + aux loss ----------------
// 1 block x 512 thr: (b, e, sub) with 4-way split of the L-dot
__global__ __launch_bounds__(512) void gating_kernel(
    const float* __restrict__ G8, const float* __restrict__ wg,
    const float* __restrict__ wn, const float* __restrict__ noise,
    int* __restrict__ IDX, float* __restrict__ GV, float* __restrict__ loss)
{
    __shared__ float pc[BB][EE][4], pn[BB][EE][4];
    __shared__ float s_clean[BB][EE], s_nstd[BB][EE], s_noisy[BB][EE], s_gates[BB][EE];
    __shared__ float s_thr_in[BB], s_thr_out[BB];
    __shared__ float s_imp[EE], s_load[EE];
    int tid = threadIdx.x;
    {
        int b = tid >> 4, e = (tid >> 2) & 3, sub = tid & 3;
        float c = 0.f, nr = 0.f;
        for (int l = sub * 84; l < sub * 84 + 84; ++l) {
            float s8 = 0.f;
            #pragma unroll
            for (int c8 = 0; c8 < 8; ++c8) s8 += G8[((size_t)c8 * BB + b) * LL + l];
            float gv = s8 * (1.0f / NN);
            c  = fmaf(gv, wg[l * EE + e], c);
            nr = fmaf(gv, wn[l * EE + e], nr);
        }
        pc[b][e][sub] = c; pn[b][e][sub] = nr;
    }
    __syncthreads();
    int b = tid >> 2, e = tid & 3;   // valid for tid < 128
    if (tid < 128) {
        float c  = ((pc[b][e][0] + pc[b][e][1]) + pc[b][e][2]) + pc[b][e][3];
        float nr = ((pn[b][e][0] + pn[b][e][1]) + pn[b][e][2]) + pn[b][e][3];
        float nstd  = softplus_f(nr) + 1e-2f;
        float noisy = fmaf(noise[b * EE + e], nstd, c);
        s_clean[b][e] = c; s_nstd[b][e] = nstd; s_noisy[b][e] = noisy;
    }
    __syncthreads();
    if (tid < 128 && e == 0) {
        float v[4];
        #pragma unroll
        for (int i = 0; i < 4; ++i) v[i] = s_noisy[b][i];
        int i0 = 0;
        for (int i = 1; i < 4; ++i) if (v[i] > v[i0]) i0 = i;
        int i1 = -1;
        for (int i = 0; i < 4; ++i) { if (i == i0) continue; if (i1 < 0 || v[i] > v[i1]) i1 = i; }
        float m3 = -1e30f;
        for (int i = 0; i < 4; ++i) { if (i == i0 || i == i1) continue; if (v[i] > m3) m3 = v[i]; }
        float e1  = expf(v[i1] - v[i0]);
        float invd = 1.0f / (1.0f + e1);
        #pragma unroll
        for (int i = 0; i < 4; ++i) s_gates[b][i] = 0.f;
        s_gates[b][i0] = invd;
        s_gates[b][i1] = e1 * invd;
        s_thr_in[b]  = m3;       // (k+1)-th value
        s_thr_out[b] = v[i1];    // k-th value
        IDX[2*b] = i0; IDX[2*b+1] = i1;
        GV[2*b] = invd; GV[2*b+1] = e1 * invd;
    }
    __syncthreads();
    if (tid < EE) {
        int ee = tid;
        float imp = 0.f, ld = 0.f;
        for (int bb2 = 0; bb2 < BB; ++bb2) {
            imp += s_gates[bb2][ee];
            float thr = (s_noisy[bb2][ee] > s_thr_in[bb2]) ? s_thr_in[bb2] : s_thr_out[bb2];
            float z = (s_clean[bb2][ee] - thr) / s_nstd[bb2][ee];
            ld += 0.5f * (1.0f + erff(z * 0.7071067811865476f));
        }
        s_imp[ee] = imp; s_load[ee] = ld;
    }
    __syncthreads();
    if (tid == 0) {
        float aux = 0.f;
        {
            float m = (s_imp[0] + s_imp[1] + s_imp[2] + s_imp[3]) * 0.25f;
            float var = 0.f;
            for (int i = 0; i < 4; ++i) { float d = s_imp[i] - m; var += d * d; }
            var *= (1.0f / 3.0f);
            aux += var / (m * m + 1e-10f);
        }
        {
            float m = (s_load[0] + s_load[1] + s_load[2] + s_load[3]) * 0.25f;
            float var = 0.f;
            for (int i = 0; i < 4; ++i) { float d = s_load[i] - m; var += d * d; }
            var *= (1.0f / 3.0f);
            aux += var / (m * m + 1e-10f);
        }
        loss[0] += 0.01f * aux;
    }
}

// ---------------- FC1 (MFMA): Hs[z] = gate * gelu(T[b] @ W1[e] + b1[e]) ----------------
// grid (4, 6, 64): x = d-tile(128), y = n-tile(64), z = b*2+slot
__global__ __launch_bounds__(256) void fc1_mfma(
    const short* __restrict__ Tb16, const short* __restrict__ W1t_l,
    const float* __restrict__ b1_l, const int* __restrict__ IDX,
    const float* __restrict__ GV, short* __restrict__ Hs)
{
    int z = blockIdx.z;
    int b = z >> 1;
    int e = IDX[z];
    float g = GV[z];
    __shared__ short Al[64][40];    // [m][k] rows padded to 40 (80B)
    __shared__ short Bl[128][40];   // [d][k]
    const short* Tb = Tb16 + (size_t)b * NN * LL;
    const short* Wb = W1t_l + (size_t)e * DHID * LL;
    const float* bb = b1_l + (size_t)e * DHID;
    int m0 = blockIdx.y * 64, n0 = blockIdx.x * 128;
    int tid = threadIdx.x;
    int wave = tid >> 6, lane = tid & 63, quad = lane >> 4, l16 = lane & 15;
    int wn = wave * 32;
    float4v zero4 = {0.f, 0.f, 0.f, 0.f};
    float4v acc[4][2];
    #pragma unroll
    for (int i = 0; i < 4; ++i)
        #pragma unroll
        for (int j = 0; j < 2; ++j) acc[i][j] = zero4;

    int am = tid >> 2, ako = (tid & 3) * 8;
    for (int k0 = 0; k0 < LL; k0 += 32) {    // 11 chunks; tail zero-padded
        {   // A: 64x32 bf16 from Tb16
            int gm = m0 + am, gk = k0 + ako;
            uint4 val = make_uint4(0, 0, 0, 0);
            if (gm < NN && gk < LL) val = *(const uint4*)(Tb + (size_t)gm * LL + gk);
            *(uint4*)&Al[am][ako] = val;
        }
        #pragma unroll
        for (int uu = 0; uu < 2; ++uu) {     // B: 128x32 bf16 copy
            int u = tid + uu * 256;
            int n = u >> 2, ko = (u & 3) * 8;
            int gk = k0 + ko;
            uint4 val = make_uint4(0, 0, 0, 0);
            if (gk < LL) val = *(const uint4*)(Wb + (size_t)(n0 + n) * LL + gk);
            *(uint4*)&Bl[n][ko] = val;
        }
        __syncthreads();
        short8 af[4], bfv[2];
        #pragma unroll
        for (int mi = 0; mi < 4; ++mi) af[mi] = *(const short8*)&Al[mi * 16 + l16][quad * 8];
        #pragma unroll
        for (int ni = 0; ni < 2; ++ni) bfv[ni] = *(const short8*)&Bl[wn + ni * 16 + l16][quad * 8];
        #pragma unroll
        for (int mi = 0; mi < 4; ++mi)
            #pragma unroll
            for (int ni = 0; ni < 2; ++ni)
                acc[mi][ni] = __builtin_amdgcn_mfma_f32_16x16x32_bf16(af[mi], bfv[ni], acc[mi][ni], 0, 0, 0);
        __syncthreads();
    }
    float bias[2];
    #pragma unroll
    for (int ni = 0; ni < 2; ++ni) bias[ni] = bb[n0 + wn + ni * 16 + l16];
    short* Ho = Hs + (size_t)z * NN * DHID;
    #pragma unroll
    for (int mi = 0; mi < 4; ++mi) {
        #pragma unroll
        for (int r = 0; r < 4; ++r) {
            int gm = m0 + mi * 16 + quad * 4 + r;   // C/D: col=lane&15, row=quad*4+reg
            if (gm >= NN) continue;
            #pragma unroll
            for (int ni = 0; ni < 2; ++ni) {
                int gd = n0 + wn + ni * 16 + l16;
                float v = acc[mi][ni][r] + bias[ni];
                Ho[(size_t)gm * DHID + gd] = f2b(g * gelu_f(v));
            }
        }
    }
}

// ---------------- FC2 (MFMA): T[b] += Hs[b,0]@W2[e0] + Hs[b,1]@W2[e1] + g-weighted b2 ----
// grid (3, 6, 32). Also refreshes Tb16 mirror.
__global__ __launch_bounds__(256) void fc2_mfma(
    const short* __restrict__ Hs, const short* __restrict__ W2t_l,
    const float* __restrict__ b2_l, float* __restrict__ T, short* __restrict__ Tb16,
    const int* __restrict__ IDX, const float* __restrict__ GV)
{
    int b = blockIdx.z;
    int e0 = IDX[2 * b], e1 = IDX[2 * b + 1];
    float g0 = GV[2 * b], g1 = GV[2 * b + 1];
    __shared__ short Al[64][40];
    __shared__ short Bl[128][40];
    int m0 = blockIdx.y * 64, n0 = blockIdx.x * 128;
    int tid = threadIdx.x;
    int wave = tid >> 6, lane = tid & 63, quad = lane >> 4, l16 = lane & 15;
    int wn = wave * 32;
    float4v zero4 = {0.f, 0.f, 0.f, 0.f};
    float4v acc[4][2];
    #pragma unroll
    for (int i = 0; i < 4; ++i)
        #pragma unroll
        for (int j = 0; j < 2; ++j) acc[i][j] = zero4;

    int am = tid >> 2, ako = (tid & 3) * 8;
    const short* HsA = Hs + (size_t)(2 * b) * NN * DHID;
    for (int kc = 0; kc < 32; ++kc) {
        int slot = kc >> 4;
        int kk = (kc & 15) * 32;
        const short* We = W2t_l + (size_t)(slot ? e1 : e0) * LL * DHID;
        {   // A: 64x32 from Hs (bf16)
            int gm = m0 + am;
            uint4 val = make_uint4(0, 0, 0, 0);
            if (gm < NN) val = *(const uint4*)(HsA + ((size_t)slot * NN + gm) * DHID + kk + ako);
            *(uint4*)&Al[am][ako] = val;
        }
        #pragma unroll
        for (int uu = 0; uu < 2; ++uu) {    // B: 128x32 from W2t [l][k]
            int u = tid + uu * 256;
            int n = u >> 2, ko = (u & 3) * 8;
            int gl = n0 + n;
            uint4 val = make_uint4(0, 0, 0, 0);
            if (gl < LL) val = *(const uint4*)(We + (size_t)gl * DHID + kk + ko);
            *(uint4*)&Bl[n][ko] = val;
        }
        __syncthreads();
        short8 af[4], bfv[2];
        #pragma unroll
        for (int mi = 0; mi < 4; ++mi) af[mi] = *(const short8*)&Al[mi * 16 + l16][quad * 8];
        #pragma unroll
        for (int ni = 0; ni < 2; ++ni) bfv[ni] = *(const short8*)&Bl[wn + ni * 16 + l16][quad * 8];
        #pragma unroll
        for (int mi = 0; mi < 4; ++mi)
            #pragma unroll
            for (int ni = 0; ni < 2; ++ni)
                acc[mi][ni] = __builtin_amdgcn_mfma_f32_16x16x32_bf16(af[mi], bfv[ni], acc[mi][ni], 0, 0, 0);
        __syncthreads();
    }
    const float* b2e0 = b2_l + (size_t)e0 * LL;
    const float* b2e1 = b2_l + (size_t)e1 * LL;
    float bias[2]; int glc[2];
    #pragma unroll
    for (int ni = 0; ni < 2; ++ni) {
        int gl = n0 + wn + ni * 16 + l16;
        glc[ni] = gl;
        bias[ni] = (gl < LL) ? (g0 * b2e0[gl] + g1 * b2e1[gl]) : 0.f;
    }
    float* Tb = T + (size_t)b * NN * LL;
    short* Tb16b = Tb16 + (size_t)b * NN * LL;
    #pragma unroll
    for (int mi = 0; mi < 4; ++mi) {
        #pragma unroll
        for (int r = 0; r < 4; ++r) {
            int gm = m0 + mi * 16 + quad * 4 + r;
            if (gm >= NN) continue;
            #pragma unroll
            for (int ni = 0; ni < 2; ++ni) {
                if (glc[ni] < LL) {
                    size_t o = (size_t)gm * LL + glc[ni];
                    float vnew = Tb[o] + acc[mi][ni][r] + bias[ni];
                    Tb[o] = vnew;
                    Tb16b[o] = f2b(vnew);
                }
            }
        }
    }
}

// ---------------- fused projection head (MFMA), transposed phase 2 ----------------
__global__ __launch_bounds__(256) void proj_fused(
    const short* __restrict__ Tb16,
    const short* __restrict__ p1wb, const float* __restrict__ p1b,
    const short* __restrict__ p2wb, const float* __restrict__ p2b,
    float* __restrict__ out)
{
    __shared__ short smem[26624];                       // 52 KB, manually carved
    short (*Al)[40]   = (short (*)[40])smem;            // 64x40   (phase 1)
    short (*Bl1)[40]  = (short (*)[40])(smem + 2560);   // 96x40   (phase 1)
    short (*B2)[104]  = (short (*)[104])smem;           // 192x104 (phase 2, overlays Al/Bl1)
    short (*Hp)[104]  = (short (*)[104])(smem + 19968); // 64x104

    int m0 = blockIdx.x * 64;
    int tid = threadIdx.x;
    int wave = tid >> 6, lane = tid & 63, quad = lane >> 4, l16 = lane & 15;
    float4v zero4 = {0.f, 0.f, 0.f, 0.f};

    // ---- phase 1: 64 x 96 = T-tile @ p1w^T ----
    float4v acc1[6];
    #pragma unroll
    for (int i = 0; i < 6; ++i) acc1[i] = zero4;
    int am = tid >> 2, ako = (tid & 3) * 8;
    for (int k0 = 0; k0 < LL; k0 += 32) {
        {
            int gm = m0 + am, gk = k0 + ako;
            uint4 val = make_uint4(0, 0, 0, 0);
            if (gm < MROWS && gk < LL) val = *(const uint4*)(Tb16 + (size_t)gm * LL + gk);
            *(uint4*)&Al[am][ako] = val;
        }
        #pragma unroll
        for (int uu = 0; uu < 2; ++uu) {
            int u = tid + uu * 256;
            if (u < 384) {
                int n = u >> 2, ko = (u & 3) * 8;
                int gk = k0 + ko;
                uint4 val = make_uint4(0, 0, 0, 0);
                if (gk < LL) val = *(const uint4*)(p1wb + (size_t)n * LL + gk);
                *(uint4*)&Bl1[n][ko] = val;
            }
        }
        __syncthreads();
        short8 af = *(const short8*)&Al[wave * 16 + l16][quad * 8];
        #pragma unroll
        for (int ni = 0; ni < 6; ++ni) {
            short8 bfv = *(const short8*)&Bl1[ni * 16 + l16][quad * 8];
            acc1[ni] = __builtin_amdgcn_mfma_f32_16x16x32_bf16(af, bfv, acc1[ni], 0, 0, 0);
        }
        __syncthreads();   // also protects Al/Bl1 before B2 overlay
    }
    // write Hp tile (LDS) + stage p2w fully into B2 (overlays Al/Bl1 — safe after sync)
    #pragma unroll
    for (int ni = 0; ni < 6; ++ni) {
        #pragma unroll
        for (int r = 0; r < 4; ++r) {
            int ml = wave * 16 + quad * 4 + r;
            int p = ni * 16 + l16;
            Hp[ml][p] = f2b(fast_tanh(acc1[ni][r] + p1b[p]));
        }
    }
    for (int u = tid; u < 192 * 12; u += 256) {
        int n = u / 12, ko = (u - n * 12) * 8;
        *(uint4*)&B2[n][ko] = *(const uint4*)(p2wb + (size_t)n * PP + ko);
    }
    __syncthreads();

    // ---- phase 2 (transposed): rows = c (192), cols = node (64), K = 96 ----
    float4v acc2[3][4];
    #pragma unroll
    for (int i = 0; i < 3; ++i)
        #pragma unroll
        for (int j = 0; j < 4; ++j) acc2[i][j] = zero4;
    #pragma unroll
    for (int kc = 0; kc < 3; ++kc) {
        int k0 = kc * 32 + quad * 8;
        short8 af[3], bfv[4];
        #pragma unroll
        for (int mi = 0; mi < 3; ++mi) af[mi] = *(const short8*)&B2[wave * 48 + mi * 16 + l16][k0];
        #pragma unroll
        for (int ni = 0; ni < 4; ++ni) bfv[ni] = *(const short8*)&Hp[ni * 16 + l16][k0];
        #pragma unroll
        for (int mi = 0; mi < 3; ++mi)
            #pragma unroll
            for (int ni = 0; ni < 4; ++ni)
                acc2[mi][ni] = __builtin_amdgcn_mfma_f32_16x16x32_bf16(af[mi], bfv[ni], acc2[mi][ni], 0, 0, 0);
    }
    // stores: lane l16 -> consecutive node (coalesced 64B runs per quad)
    int bqv[4], ndv[4]; bool okv[4];
    #pragma unroll
    for (int ni = 0; ni < 4; ++ni) {
        int gm = m0 + ni * 16 + l16;
        okv[ni] = (gm < MROWS);
        int bq = gm / NN;
        bqv[ni] = bq; ndv[ni] = gm - bq * NN;
    }
    #pragma unroll
    for (int mi = 0; mi < 3; ++mi) {
        #pragma unroll
        for (int r = 0; r < 4; ++r) {
            int c = wave * 48 + mi * 16 + quad * 4 + r;
            float pb = p2b[c];
            int p = c >> 1;
            if ((r & 1) == 0) {               // c even -> mean
                #pragma unroll
                for (int ni = 0; ni < 4; ++ni) {
                    if (!okv[ni]) continue;
                    float v = acc2[mi][ni][r] + pb;
                    out[((size_t)bqv[ni] * PP + p) * NN + ndv[ni]] = v;
                }
            } else {                          // c odd -> std
                #pragma unroll
                for (int ni = 0; ni < 4; ++ni) {
                    if (!okv[ni]) continue;
                    float v = acc2[mi][ni][r] + pb;
                    out[BPN + 1 + ((size_t)bqv[ni] * PP + p) * NN + ndv[ni]] = softplus_f(v) + 1e-6f;
                }
            }
        }
    }
}

__global__ void loss_write_kernel(const float* __restrict__ loss, float* __restrict__ out)
{
    if (threadIdx.x == 0) out[BPN] = loss[0];
}

extern "C" void kernel_launch(void* const* d_in, const int* in_sizes, int n_in,
                              void* d_out, int out_size, void* d_ws, size_t ws_size,
                              hipStream_t stream)
{
    const float* x     = (const float*)d_in[0];
    const float* noise = (const float*)d_in[1];
    const float* wg    = (const float*)d_in[2];
    const float* wn    = (const float*)d_in[3];
    const float* W1    = (const float*)d_in[4];
    const float* b1    = (const float*)d_in[5];
    const float* W2    = (const float*)d_in[6];
    const float* b2    = (const float*)d_in[7];
    const float* p1w   = (const float*)d_in[8];
    const float* p1b   = (const float*)d_in[9];
    const float* p2w   = (const float*)d_in[10];
    const float* p2b   = (const float*)d_in[11];
    float* out = (float*)d_out;

    float* ws   = (float*)d_ws;
    float* T    = ws;                          // STOT fp32
    float* G8   = T + STOT;                    // 8*BB*LL
    float* LOSS = G8 + 8 * BB * LL;            // 8
    float* GV   = LOSS + 8;                    // 64
    int*   IDX  = (int*)(GV + 64);             // 64
    float* MU   = (float*)(IDX + 64);          // BB*NN
    float* IV   = MU + MROWS;                  // BB*NN
    short* W1t  = (short*)(IV + MROWS);        // EE*DHID*LL (per-layer reuse)
    short* W2t  = W1t + EE * DHID * LL;        // EE*LL*DHID (per-layer reuse)
    short* p1wb = W2t + EE * DHID * LL;        // 96*336
    short* p2wb = p1wb + PP * LL;              // 192*96
    short* Tb16 = p2wb + 2 * PP * PP;          // STOT bf16 mirror of T
    short* Hs   = Tb16 + STOT;                 // 64*321*512 bf16

    revin_stats<<<dim3(BB, 6), 256, 0, stream>>>(x, MU, IV, LOSS);
    revin_tn<<<dim3(BB, 6, 7), 256, 0, stream>>>(x, MU, IV, T, Tb16);

    pcvt_kernel<<<(PP * LL + 2 * PP * PP + 255) / 256, 256, 0, stream>>>(p1w, p2w, p1wb, p2wb);

    for (int l = 0; l < NLAYERS; ++l) {
        // per-layer weight transpose+convert (reused buffers)
        wtrans_kernel<<<dim3(8, 6, EE), 256, 0, stream>>>(
            W1 + (size_t)l * EE * LL * DHID, W1t, LL, DHID);    // K=336, D=512
        wtrans_kernel<<<dim3(6, 8, EE), 256, 0, stream>>>(
            W2 + (size_t)l * EE * DHID * LL, W2t, DHID, LL);    // K=512, D=336
        gmean_part<<<dim3(BB, 8), 384, 0, stream>>>(T, G8);
        gating_kernel<<<1, 512, 0, stream>>>(G8, wg + (size_t)l * LL * EE, wn + (size_t)l * LL * EE,
                                             noise + (size_t)l * BB * EE, IDX, GV, LOSS);
        fc1_mfma<<<dim3(4, 6, 64), 256, 0, stream>>>(
            Tb16, W1t, b1 + (size_t)l * EE * DHID, IDX, GV, Hs);
        fc2_mfma<<<dim3(3, 6, 32), 256, 0, stream>>>(
            Hs, W2t, b2 + (size_t)l * EE * LL, T, Tb16, IDX, GV);
    }
    proj_fused<<<161, 256, 0, stream>>>(Tb16, p1wb, p1b, p2wb, p2b, out);
    loss_write_kernel<<<1, 64, 0, stream>>>(LOSS, out);
}

// Round 6
// 484.164 us; speedup vs baseline: 1.3665x; 1.3665x over previous
//
#include <hip/hip_runtime.h>
#include <hip/hip_bf16.h>

#define NLAYERS 3
#define BB 32
#define LL 336
#define NN 321
#define EE 4
#define DHID 512
#define PP 96
#define STOT (BB*NN*LL)        // 3451392
#define MROWS (BB*NN)          // 10272
#define BPN ((size_t)BB*PP*NN) // 986112

typedef __attribute__((ext_vector_type(8))) short short8;
typedef __attribute__((ext_vector_type(4))) float float4v;

union S8 { short8 v; uint4 u; short s[8]; };
union BF { __hip_bfloat16 h; short s; };

__device__ __forceinline__ short f2b(float f) { BF u; u.h = __float2bfloat16(f); return u.s; }

__device__ __forceinline__ float fast_tanh(float y) {
    float e = __expf(2.0f * y);
    return 1.0f - 2.0f / (e + 1.0f);   // exact limits at +-inf
}
__device__ __forceinline__ float gelu_f(float x) {
    return 0.5f * x * (1.0f + fast_tanh(0.7978845608028654f * (x + 0.044715f * x * x * x)));
}
__device__ __forceinline__ float softplus_f(float x) {
    return fmaxf(x, 0.0f) + log1pf(expf(-fabsf(x)));
}

// ---------------- RevIN stats: mu/inv per (b,n); also zeros loss ----------------
__global__ __launch_bounds__(256) void revin_stats(
    const float* __restrict__ x, float* __restrict__ MU, float* __restrict__ IV,
    float* __restrict__ loss)
{
    int b = blockIdx.x, nt = blockIdx.y;
    int tid = threadIdx.x;
    if (b == 0 && nt == 0 && tid == 0) loss[0] = 0.0f;
    int ni = tid & 63, lc = tid >> 6;
    int n = nt * 64 + ni;
    float s = 0.f, ss = 0.f;
    if (n < NN) {
        const float* xp = x + ((size_t)b * LL + lc * 84) * NN + n;
        for (int l = 0; l < 84; ++l, xp += NN) {
            float v = *xp; s += v; ss = fmaf(v, v, ss);
        }
    }
    __shared__ float Ss[4][64], Sq[4][64];
    Ss[lc][ni] = s; Sq[lc][ni] = ss;
    __syncthreads();
    if (lc == 0 && n < NN) {
        float st = ((Ss[0][ni] + Ss[1][ni]) + Ss[2][ni]) + Ss[3][ni];
        float sq = ((Sq[0][ni] + Sq[1][ni]) + Sq[2][ni]) + Sq[3][ni];
        float mu  = st * (1.0f / LL);
        float var = sq * (1.0f / LL) - mu * mu;   // ddof=0
        float inv = 1.0f / sqrtf(var + 1e-5f);
        MU[b * NN + n] = mu;
        IV[b * NN + n] = inv;
    }
}

// ---------------- RevIN transpose+normalize: T[b*NN+n][l] (fp32+bf16) ----------------
__global__ __launch_bounds__(256) void revin_tn(
    const float* __restrict__ x, const float* __restrict__ MU, const float* __restrict__ IV,
    float* __restrict__ T, short* __restrict__ Tb16)
{
    int b = blockIdx.x, nt = blockIdx.y, lt = blockIdx.z;
    int n0 = nt * 64, l0 = lt * 48;
    __shared__ float Ls[48][65];
    int tid = threadIdx.x;
    #pragma unroll
    for (int i = 0; i < 12; ++i) {
        int lin = tid + i * 256;
        int li = lin >> 6, ni = lin & 63;
        int n = n0 + ni;
        Ls[li][ni] = (n < NN) ? x[((size_t)b * LL + l0 + li) * NN + n] : 0.f;
    }
    __syncthreads();
    int r = tid >> 2, q = tid & 3;
    int n = n0 + r;
    if (n >= NN) return;
    float mu = MU[b * NN + n], iv = IV[b * NN + n];
    size_t row = (size_t)(b * NN + n) * LL + l0;
    #pragma unroll
    for (int k = 0; k < 3; ++k) {
        int c = (q + 4 * k) * 4;
        float4 v;
        v.x = (Ls[c    ][r] - mu) * iv;
        v.y = (Ls[c + 1][r] - mu) * iv;
        v.z = (Ls[c + 2][r] - mu) * iv;
        v.w = (Ls[c + 3][r] - mu) * iv;
        *(float4*)&T[row + c] = v;
        union { short s[4]; uint2 u; } pk;
        pk.s[0] = f2b(v.x); pk.s[1] = f2b(v.y); pk.s[2] = f2b(v.z); pk.s[3] = f2b(v.w);
        *(uint2*)&Tb16[row + c] = pk.u;
    }
}

// ---------------- tiled transpose+convert: dst[d][k] <- bf16(src[k][d]) ----------------
__global__ __launch_bounds__(256) void wtrans_kernel(
    const float* __restrict__ src0, short* __restrict__ dst0, int K, int D)
{
    int le = blockIdx.z;
    const float* src = src0 + (size_t)le * K * D;
    short* dst = dst0 + (size_t)le * K * D;
    int d0 = blockIdx.x * 64, k0 = blockIdx.y * 64;
    __shared__ short Ws[64][72];
    int tid = threadIdx.x;
    #pragma unroll
    for (int i = 0; i < 16; ++i) {
        int lin = tid + i * 256;
        int ki = lin >> 6, dj = lin & 63;
        int k = k0 + ki, d = d0 + dj;
        Ws[ki][dj] = (k < K && d < D) ? f2b(src[(size_t)k * D + d]) : (short)0;
    }
    __syncthreads();
    int di = tid >> 2, d = d0 + di;
    if (d >= D) return;
    #pragma unroll
    for (int kp = 0; kp < 2; ++kp) {
        int kj = ((tid & 3) + 4 * kp) * 8;
        if (k0 + kj >= K) continue;
        union { short s[8]; uint4 u; } pk;
        #pragma unroll
        for (int j = 0; j < 8; ++j) pk.s[j] = Ws[kj + j][di];
        *(uint4*)(dst + (size_t)d * K + k0 + kj) = pk.u;
    }
}

// ---------------- small convert for p1w/p2w (already [n][k]) ----------------
__global__ __launch_bounds__(256) void pcvt_kernel(
    const float* __restrict__ p1w, const float* __restrict__ p2w,
    short* __restrict__ p1wb, short* __restrict__ p2wb)
{
    int i = blockIdx.x * 256 + threadIdx.x;
    if (i < PP * LL) p1wb[i] = f2b(p1w[i]);
    else if (i < PP * LL + 2 * PP * PP) { int j = i - PP * LL; p2wb[j] = f2b(p2w[j]); }
}

// ---------------- gate features: 8-way partial sums over n ----------------
__global__ __launch_bounds__(384) void gmean_part(
    const float* __restrict__ T, float* __restrict__ G8)
{
    int b = blockIdx.x, c = blockIdx.y;
    int l = threadIdx.x;
    if (l >= LL) return;
    int n_lo = c * 41, n_hi = (NN < n_lo + 41) ? NN : (n_lo + 41);
    const float* tp = T + ((size_t)b * NN + n_lo) * LL + l;
    float s = 0.f;
    for (int n = n_lo; n < n_hi; ++n, tp += LL) s += *tp;
    G8[((size_t)c * BB + b) * LL + l] = s;
}

__global__ __launch_bounds__(384) void gmean_red(
    const float* __restrict__ G8, float* __restrict__ G)
{
    int b = blockIdx.x;
    int l = threadIdx.x;
    if (l >= LL) return;
    float s = 0.f;
    #pragma unroll
    for (int c = 0; c < 8; ++c) s += G8[((size_t)c * BB + b) * LL + l];
    G[b * LL + l] = s * (1.0f / NN);
}

// ---------------- noisy top-k gating + aux loss (512 thr, 4-way dot split) ----------------
__global__ __launch_bounds__(512) void gating_kernel(
    const float* __restrict__ G, const float* __restrict__ wg,
    const float* __restrict__ wn, const float* __restrict__ noise,
    int* __restrict__ IDX, float* __restrict__ GV, float* __restrict__ loss)
{
    __shared__ float pc[BB][EE][4], pn[BB][EE][4];
    __shared__ float s_clean[BB][EE], s_nstd[BB][EE], s_noisy[BB][EE], s_gates[BB][EE];
    __shared__ float s_thr_in[BB], s_thr_out[BB];
    __shared__ float s_imp[EE], s_load[EE];
    int tid = threadIdx.x;
    {
        int b = tid >> 4, e = (tid >> 2) & 3, sub = tid & 3;
        float c = 0.f, nr = 0.f;
        const float* gp = G + b * LL;
        for (int l = sub * 84; l < sub * 84 + 84; ++l) {
            float gv = gp[l];
            c  = fmaf(gv, wg[l * EE + e], c);
            nr = fmaf(gv, wn[l * EE + e], nr);
        }
        pc[b][e][sub] = c; pn[b][e][sub] = nr;
    }
    __syncthreads();
    int b = tid >> 2, e = tid & 3;   // valid for tid < 128
    if (tid < 128) {
        float c  = ((pc[b][e][0] + pc[b][e][1]) + pc[b][e][2]) + pc[b][e][3];
        float nr = ((pn[b][e][0] + pn[b][e][1]) + pn[b][e][2]) + pn[b][e][3];
        float nstd  = softplus_f(nr) + 1e-2f;
        float noisy = fmaf(noise[b * EE + e], nstd, c);
        s_clean[b][e] = c; s_nstd[b][e] = nstd; s_noisy[b][e] = noisy;
    }
    __syncthreads();
    if (tid < 128 && e == 0) {
        float v[4];
        #pragma unroll
        for (int i = 0; i < 4; ++i) v[i] = s_noisy[b][i];
        int i0 = 0;
        for (int i = 1; i < 4; ++i) if (v[i] > v[i0]) i0 = i;
        int i1 = -1;
        for (int i = 0; i < 4; ++i) { if (i == i0) continue; if (i1 < 0 || v[i] > v[i1]) i1 = i; }
        float m3 = -1e30f;
        for (int i = 0; i < 4; ++i) { if (i == i0 || i == i1) continue; if (v[i] > m3) m3 = v[i]; }
        float e1  = expf(v[i1] - v[i0]);
        float invd = 1.0f / (1.0f + e1);
        #pragma unroll
        for (int i = 0; i < 4; ++i) s_gates[b][i] = 0.f;
        s_gates[b][i0] = invd;
        s_gates[b][i1] = e1 * invd;
        s_thr_in[b]  = m3;       // (k+1)-th value
        s_thr_out[b] = v[i1];    // k-th value
        IDX[2*b] = i0; IDX[2*b+1] = i1;
        GV[2*b] = invd; GV[2*b+1] = e1 * invd;
    }
    __syncthreads();
    if (tid < EE) {
        int ee = tid;
        float imp = 0.f, ld = 0.f;
        for (int bb2 = 0; bb2 < BB; ++bb2) {
            imp += s_gates[bb2][ee];
            float thr = (s_noisy[bb2][ee] > s_thr_in[bb2]) ? s_thr_in[bb2] : s_thr_out[bb2];
            float z = (s_clean[bb2][ee] - thr) / s_nstd[bb2][ee];
            ld += 0.5f * (1.0f + erff(z * 0.7071067811865476f));
        }
        s_imp[ee] = imp; s_load[ee] = ld;
    }
    __syncthreads();
    if (tid == 0) {
        float aux = 0.f;
        {
            float m = (s_imp[0] + s_imp[1] + s_imp[2] + s_imp[3]) * 0.25f;
            float var = 0.f;
            for (int i = 0; i < 4; ++i) { float d = s_imp[i] - m; var += d * d; }
            var *= (1.0f / 3.0f);
            aux += var / (m * m + 1e-10f);
        }
        {
            float m = (s_load[0] + s_load[1] + s_load[2] + s_load[3]) * 0.25f;
            float var = 0.f;
            for (int i = 0; i < 4; ++i) { float d = s_load[i] - m; var += d * d; }
            var *= (1.0f / 3.0f);
            aux += var / (m * m + 1e-10f);
        }
        loss[0] += 0.01f * aux;
    }
}

// ---------------- FC1 (MFMA): Hs[z] = gate * gelu(T[b] @ W1[e] + b1[e]) ----------------
// grid (4, 6, 64): x = d-tile(128), y = n-tile(64), z = b*2+slot
__global__ __launch_bounds__(256) void fc1_mfma(
    const short* __restrict__ Tb16, const short* __restrict__ W1t_l,
    const float* __restrict__ b1_l, const int* __restrict__ IDX,
    const float* __restrict__ GV, short* __restrict__ Hs)
{
    int z = blockIdx.z;
    int b = z >> 1;
    int e = IDX[z];
    float g = GV[z];
    __shared__ short Al[64][40];    // [m][k] rows padded to 40 (80B)
    __shared__ short Bl[128][40];   // [d][k]
    const short* Tb = Tb16 + (size_t)b * NN * LL;
    const short* Wb = W1t_l + (size_t)e * DHID * LL;
    const float* bb = b1_l + (size_t)e * DHID;
    int m0 = blockIdx.y * 64, n0 = blockIdx.x * 128;
    int tid = threadIdx.x;
    int wave = tid >> 6, lane = tid & 63, quad = lane >> 4, l16 = lane & 15;
    int wn = wave * 32;
    float4v zero4 = {0.f, 0.f, 0.f, 0.f};
    float4v acc[4][2];
    #pragma unroll
    for (int i = 0; i < 4; ++i)
        #pragma unroll
        for (int j = 0; j < 2; ++j) acc[i][j] = zero4;

    int am = tid >> 2, ako = (tid & 3) * 8;
    for (int k0 = 0; k0 < LL; k0 += 32) {    // 11 chunks; tail zero-padded
        {   // A: 64x32 bf16 from Tb16
            int gm = m0 + am, gk = k0 + ako;
            uint4 val = make_uint4(0, 0, 0, 0);
            if (gm < NN && gk < LL) val = *(const uint4*)(Tb + (size_t)gm * LL + gk);
            *(uint4*)&Al[am][ako] = val;
        }
        #pragma unroll
        for (int uu = 0; uu < 2; ++uu) {     // B: 128x32 bf16 copy
            int u = tid + uu * 256;
            int n = u >> 2, ko = (u & 3) * 8;
            int gk = k0 + ko;
            uint4 val = make_uint4(0, 0, 0, 0);
            if (gk < LL) val = *(const uint4*)(Wb + (size_t)(n0 + n) * LL + gk);
            *(uint4*)&Bl[n][ko] = val;
        }
        __syncthreads();
        short8 af[4], bfv[2];
        #pragma unroll
        for (int mi = 0; mi < 4; ++mi) af[mi] = *(const short8*)&Al[mi * 16 + l16][quad * 8];
        #pragma unroll
        for (int ni = 0; ni < 2; ++ni) bfv[ni] = *(const short8*)&Bl[wn + ni * 16 + l16][quad * 8];
        #pragma unroll
        for (int mi = 0; mi < 4; ++mi)
            #pragma unroll
            for (int ni = 0; ni < 2; ++ni)
                acc[mi][ni] = __builtin_amdgcn_mfma_f32_16x16x32_bf16(af[mi], bfv[ni], acc[mi][ni], 0, 0, 0);
        __syncthreads();
    }
    float bias[2];
    #pragma unroll
    for (int ni = 0; ni < 2; ++ni) bias[ni] = bb[n0 + wn + ni * 16 + l16];
    short* Ho = Hs + (size_t)z * NN * DHID;
    #pragma unroll
    for (int mi = 0; mi < 4; ++mi) {
        #pragma unroll
        for (int r = 0; r < 4; ++r) {
            int gm = m0 + mi * 16 + quad * 4 + r;   // C/D: col=lane&15, row=quad*4+reg
            if (gm >= NN) continue;
            #pragma unroll
            for (int ni = 0; ni < 2; ++ni) {
                int gd = n0 + wn + ni * 16 + l16;
                float v = acc[mi][ni][r] + bias[ni];
                Ho[(size_t)gm * DHID + gd] = f2b(g * gelu_f(v));
            }
        }
    }
}

// ---------------- FC2 (MFMA): T[b] += Hs[b,0]@W2[e0] + Hs[b,1]@W2[e1] + g-weighted b2 ----
// grid (3, 6, 32). Also refreshes Tb16 mirror.
__global__ __launch_bounds__(256) void fc2_mfma(
    const short* __restrict__ Hs, const short* __restrict__ W2t_l,
    const float* __restrict__ b2_l, float* __restrict__ T, short* __restrict__ Tb16,
    const int* __restrict__ IDX, const float* __restrict__ GV)
{
    int b = blockIdx.z;
    int e0 = IDX[2 * b], e1 = IDX[2 * b + 1];
    float g0 = GV[2 * b], g1 = GV[2 * b + 1];
    __shared__ short Al[64][40];
    __shared__ short Bl[128][40];
    int m0 = blockIdx.y * 64, n0 = blockIdx.x * 128;
    int tid = threadIdx.x;
    int wave = tid >> 6, lane = tid & 63, quad = lane >> 4, l16 = lane & 15;
    int wn = wave * 32;
    float4v zero4 = {0.f, 0.f, 0.f, 0.f};
    float4v acc[4][2];
    #pragma unroll
    for (int i = 0; i < 4; ++i)
        #pragma unroll
        for (int j = 0; j < 2; ++j) acc[i][j] = zero4;

    int am = tid >> 2, ako = (tid & 3) * 8;
    const short* HsA = Hs + (size_t)(2 * b) * NN * DHID;
    for (int kc = 0; kc < 32; ++kc) {
        int slot = kc >> 4;
        int kk = (kc & 15) * 32;
        const short* We = W2t_l + (size_t)(slot ? e1 : e0) * LL * DHID;
        {   // A: 64x32 from Hs (bf16)
            int gm = m0 + am;
            uint4 val = make_uint4(0, 0, 0, 0);
            if (gm < NN) val = *(const uint4*)(HsA + ((size_t)slot * NN + gm) * DHID + kk + ako);
            *(uint4*)&Al[am][ako] = val;
        }
        #pragma unroll
        for (int uu = 0; uu < 2; ++uu) {    // B: 128x32 from W2t [l][k]
            int u = tid + uu * 256;
            int n = u >> 2, ko = (u & 3) * 8;
            int gl = n0 + n;
            uint4 val = make_uint4(0, 0, 0, 0);
            if (gl < LL) val = *(const uint4*)(We + (size_t)gl * DHID + kk + ko);
            *(uint4*)&Bl[n][ko] = val;
        }
        __syncthreads();
        short8 af[4], bfv[2];
        #pragma unroll
        for (int mi = 0; mi < 4; ++mi) af[mi] = *(const short8*)&Al[mi * 16 + l16][quad * 8];
        #pragma unroll
        for (int ni = 0; ni < 2; ++ni) bfv[ni] = *(const short8*)&Bl[wn + ni * 16 + l16][quad * 8];
        #pragma unroll
        for (int mi = 0; mi < 4; ++mi)
            #pragma unroll
            for (int ni = 0; ni < 2; ++ni)
                acc[mi][ni] = __builtin_amdgcn_mfma_f32_16x16x32_bf16(af[mi], bfv[ni], acc[mi][ni], 0, 0, 0);
        __syncthreads();
    }
    const float* b2e0 = b2_l + (size_t)e0 * LL;
    const float* b2e1 = b2_l + (size_t)e1 * LL;
    float bias[2]; int glc[2];
    #pragma unroll
    for (int ni = 0; ni < 2; ++ni) {
        int gl = n0 + wn + ni * 16 + l16;
        glc[ni] = gl;
        bias[ni] = (gl < LL) ? (g0 * b2e0[gl] + g1 * b2e1[gl]) : 0.f;
    }
    float* Tb = T + (size_t)b * NN * LL;
    short* Tb16b = Tb16 + (size_t)b * NN * LL;
    #pragma unroll
    for (int mi = 0; mi < 4; ++mi) {
        #pragma unroll
        for (int r = 0; r < 4; ++r) {
            int gm = m0 + mi * 16 + quad * 4 + r;
            if (gm >= NN) continue;
            #pragma unroll
            for (int ni = 0; ni < 2; ++ni) {
                if (glc[ni] < LL) {
                    size_t o = (size_t)gm * LL + glc[ni];
                    float vnew = Tb[o] + acc[mi][ni][r] + bias[ni];
                    Tb[o] = vnew;
                    Tb16b[o] = f2b(vnew);
                }
            }
        }
    }
}

// ---------------- fused projection head (MFMA), transposed phase 2 ----------------
__global__ __launch_bounds__(256) void proj_fused(
    const short* __restrict__ Tb16,
    const short* __restrict__ p1wb, const float* __restrict__ p1b,
    const short* __restrict__ p2wb, const float* __restrict__ p2b,
    float* __restrict__ out)
{
    __shared__ short smem[26624];                       // 52 KB, manually carved
    short (*Al)[40]   = (short (*)[40])smem;            // 64x40   (phase 1)
    short (*Bl1)[40]  = (short (*)[40])(smem + 2560);   // 96x40   (phase 1)
    short (*B2)[104]  = (short (*)[104])smem;           // 192x104 (phase 2, overlays Al/Bl1)
    short (*Hp)[104]  = (short (*)[104])(smem + 19968); // 64x104

    int m0 = blockIdx.x * 64;
    int tid = threadIdx.x;
    int wave = tid >> 6, lane = tid & 63, quad = lane >> 4, l16 = lane & 15;
    float4v zero4 = {0.f, 0.f, 0.f, 0.f};

    // ---- phase 1: 64 x 96 = T-tile @ p1w^T ----
    float4v acc1[6];
    #pragma unroll
    for (int i = 0; i < 6; ++i) acc1[i] = zero4;
    int am = tid >> 2, ako = (tid & 3) * 8;
    for (int k0 = 0; k0 < LL; k0 += 32) {
        {
            int gm = m0 + am, gk = k0 + ako;
            uint4 val = make_uint4(0, 0, 0, 0);
            if (gm < MROWS && gk < LL) val = *(const uint4*)(Tb16 + (size_t)gm * LL + gk);
            *(uint4*)&Al[am][ako] = val;
        }
        #pragma unroll
        for (int uu = 0; uu < 2; ++uu) {
            int u = tid + uu * 256;
            if (u < 384) {
                int n = u >> 2, ko = (u & 3) * 8;
                int gk = k0 + ko;
                uint4 val = make_uint4(0, 0, 0, 0);
                if (gk < LL) val = *(const uint4*)(p1wb + (size_t)n * LL + gk);
                *(uint4*)&Bl1[n][ko] = val;
            }
        }
        __syncthreads();
        short8 af = *(const short8*)&Al[wave * 16 + l16][quad * 8];
        #pragma unroll
        for (int ni = 0; ni < 6; ++ni) {
            short8 bfv = *(const short8*)&Bl1[ni * 16 + l16][quad * 8];
            acc1[ni] = __builtin_amdgcn_mfma_f32_16x16x32_bf16(af, bfv, acc1[ni], 0, 0, 0);
        }
        __syncthreads();   // also protects Al/Bl1 before B2 overlay
    }
    // write Hp tile (LDS) + stage p2w fully into B2 (overlays Al/Bl1 — safe after sync)
    #pragma unroll
    for (int ni = 0; ni < 6; ++ni) {
        #pragma unroll
        for (int r = 0; r < 4; ++r) {
            int ml = wave * 16 + quad * 4 + r;
            int p = ni * 16 + l16;
            Hp[ml][p] = f2b(fast_tanh(acc1[ni][r] + p1b[p]));
        }
    }
    for (int u = tid; u < 192 * 12; u += 256) {
        int n = u / 12, ko = (u - n * 12) * 8;
        *(uint4*)&B2[n][ko] = *(const uint4*)(p2wb + (size_t)n * PP + ko);
    }
    __syncthreads();

    // ---- phase 2 (transposed): rows = c (192), cols = node (64), K = 96 ----
    float4v acc2[3][4];
    #pragma unroll
    for (int i = 0; i < 3; ++i)
        #pragma unroll
        for (int j = 0; j < 4; ++j) acc2[i][j] = zero4;
    #pragma unroll
    for (int kc = 0; kc < 3; ++kc) {
        int k0 = kc * 32 + quad * 8;
        short8 af[3], bfv[4];
        #pragma unroll
        for (int mi = 0; mi < 3; ++mi) af[mi] = *(const short8*)&B2[wave * 48 + mi * 16 + l16][k0];
        #pragma unroll
        for (int ni = 0; ni < 4; ++ni) bfv[ni] = *(const short8*)&Hp[ni * 16 + l16][k0];
        #pragma unroll
        for (int mi = 0; mi < 3; ++mi)
            #pragma unroll
            for (int ni = 0; ni < 4; ++ni)
                acc2[mi][ni] = __builtin_amdgcn_mfma_f32_16x16x32_bf16(af[mi], bfv[ni], acc2[mi][ni], 0, 0, 0);
    }
    // stores: lane l16 -> consecutive node (coalesced 64B runs per quad)
    int bqv[4], ndv[4]; bool okv[4];
    #pragma unroll
    for (int ni = 0; ni < 4; ++ni) {
        int gm = m0 + ni * 16 + l16;
        okv[ni] = (gm < MROWS);
        int bq = gm / NN;
        bqv[ni] = bq; ndv[ni] = gm - bq * NN;
    }
    #pragma unroll
    for (int mi = 0; mi < 3; ++mi) {
        #pragma unroll
        for (int r = 0; r < 4; ++r) {
            int c = wave * 48 + mi * 16 + quad * 4 + r;
            float pb = p2b[c];
            int p = c >> 1;
            if ((r & 1) == 0) {               // c even -> mean
                #pragma unroll
                for (int ni = 0; ni < 4; ++ni) {
                    if (!okv[ni]) continue;
                    float v = acc2[mi][ni][r] + pb;
                    out[((size_t)bqv[ni] * PP + p) * NN + ndv[ni]] = v;
                }
            } else {                          // c odd -> std
                #pragma unroll
                for (int ni = 0; ni < 4; ++ni) {
                    if (!okv[ni]) continue;
                    float v = acc2[mi][ni][r] + pb;
                    out[BPN + 1 + ((size_t)bqv[ni] * PP + p) * NN + ndv[ni]] = softplus_f(v) + 1e-6f;
                }
            }
        }
    }
}

__global__ void loss_write_kernel(const float* __restrict__ loss, float* __restrict__ out)
{
    if (threadIdx.x == 0) out[BPN] = loss[0];
}

extern "C" void kernel_launch(void* const* d_in, const int* in_sizes, int n_in,
                              void* d_out, int out_size, void* d_ws, size_t ws_size,
                              hipStream_t stream)
{
    const float* x     = (const float*)d_in[0];
    const float* noise = (const float*)d_in[1];
    const float* wg    = (const float*)d_in[2];
    const float* wn    = (const float*)d_in[3];
    const float* W1    = (const float*)d_in[4];
    const float* b1    = (const float*)d_in[5];
    const float* W2    = (const float*)d_in[6];
    const float* b2    = (const float*)d_in[7];
    const float* p1w   = (const float*)d_in[8];
    const float* p1b   = (const float*)d_in[9];
    const float* p2w   = (const float*)d_in[10];
    const float* p2b   = (const float*)d_in[11];
    float* out = (float*)d_out;

    float* ws   = (float*)d_ws;
    float* T    = ws;                          // STOT fp32
    float* G8   = T + STOT;                    // 8*BB*LL
    float* G    = G8 + 8 * BB * LL;            // BB*LL
    float* LOSS = G + BB * LL;                 // 8
    float* GV   = LOSS + 8;                    // 64
    int*   IDX  = (int*)(GV + 64);             // 64
    float* MU   = (float*)(IDX + 64);          // BB*NN
    float* IV   = MU + MROWS;                  // BB*NN
    short* W1t  = (short*)(IV + MROWS);        // NLAYERS*EE*DHID*LL bf16 [le][d][k]
    short* W2t  = W1t + NLAYERS * EE * DHID * LL;
    short* p1wb = W2t + NLAYERS * EE * DHID * LL;   // 96*336
    short* p2wb = p1wb + PP * LL;              // 192*96
    short* Tb16 = p2wb + 2 * PP * PP;          // STOT bf16 mirror of T
    short* Hs   = Tb16 + STOT;                 // 64*321*512 bf16

    revin_stats<<<dim3(BB, 6), 256, 0, stream>>>(x, MU, IV, LOSS);
    revin_tn<<<dim3(BB, 6, 7), 256, 0, stream>>>(x, MU, IV, T, Tb16);

    pcvt_kernel<<<(PP * LL + 2 * PP * PP + 255) / 256, 256, 0, stream>>>(p1w, p2w, p1wb, p2wb);
    // all-layer weight transposes up front (overlap with layer-0 compute)
    wtrans_kernel<<<dim3(8, 6, NLAYERS * EE), 256, 0, stream>>>(W1, W1t, LL, DHID);
    wtrans_kernel<<<dim3(6, 8, NLAYERS * EE), 256, 0, stream>>>(W2, W2t, DHID, LL);

    for (int l = 0; l < NLAYERS; ++l) {
        gmean_part<<<dim3(BB, 8), 384, 0, stream>>>(T, G8);
        gmean_red<<<BB, 384, 0, stream>>>(G8, G);
        gating_kernel<<<1, 512, 0, stream>>>(G, wg + (size_t)l * LL * EE, wn + (size_t)l * LL * EE,
                                             noise + (size_t)l * BB * EE, IDX, GV, LOSS);
        fc1_mfma<<<dim3(4, 6, 64), 256, 0, stream>>>(
            Tb16, W1t + (size_t)l * EE * DHID * LL, b1 + (size_t)l * EE * DHID, IDX, GV, Hs);
        fc2_mfma<<<dim3(3, 6, 32), 256, 0, stream>>>(
            Hs, W2t + (size_t)l * EE * LL * DHID, b2 + (size_t)l * EE * LL, T, Tb16, IDX, GV);
    }
    proj_fused<<<161, 256, 0, stream>>>(Tb16, p1wb, p1b, p2wb, p2b, out);
    loss_write_kernel<<<1, 64, 0, stream>>>(LOSS, out);
}